// Round 4
// baseline (988.237 us; speedup 1.0000x reference)
//
#include <hip/hip_runtime.h>

typedef unsigned short u16;
typedef u16 u16x4 __attribute__((ext_vector_type(4)));
typedef u16 u16x8 __attribute__((ext_vector_type(8)));
typedef __bf16 bf16x8 __attribute__((ext_vector_type(8)));
typedef float f32x4 __attribute__((ext_vector_type(4)));

#define MFMA16 __builtin_amdgcn_mfma_f32_16x16x32_bf16
#define QSCALE 0.17677669529663689f

__device__ __forceinline__ u16 f2bf(float f) {
  unsigned u = __builtin_bit_cast(unsigned, f);
  u += 0x7fffu + ((u >> 16) & 1u);
  return (u16)(u >> 16);
}
__device__ __forceinline__ bf16x8 as_bf(u16x8 u) { return __builtin_bit_cast(bf16x8, u); }
__device__ __forceinline__ f32x4 zf4() { f32x4 z = {0.f, 0.f, 0.f, 0.f}; return z; }

// DPP lane permute (VALU, no LDS pipe). Reductions over the 16-lane row.
template <int CTRL>
__device__ __forceinline__ float dppf(float x) {
  int i = __builtin_bit_cast(int, x);
  int r = __builtin_amdgcn_update_dpp(i, i, CTRL, 0xf, 0xf, false);
  return __builtin_bit_cast(float, r);
}
__device__ __forceinline__ float rmax16(float x) {
  x = fmaxf(x, dppf<0xB1>(x));    // quad_perm xor1
  x = fmaxf(x, dppf<0x4E>(x));    // quad_perm xor2
  x = fmaxf(x, dppf<0x124>(x));   // row_ror:4
  x = fmaxf(x, dppf<0x128>(x));   // row_ror:8
  return x;
}
__device__ __forceinline__ float rsum16(float x) {
  x += dppf<0xB1>(x);
  x += dppf<0x4E>(x);
  x += dppf<0x124>(x);
  x += dppf<0x128>(x);
  return x;
}

// ---------------- prep: weight transpose->bf16, smask build ----------------
__global__ __launch_bounds__(256) void prep_kernel(
    const float* __restrict__ wq, const float* __restrict__ wp,
    const float* __restrict__ bt, const int* __restrict__ ri,
    const float* __restrict__ mask,
    u16* __restrict__ wqT, u16* __restrict__ wpT, float* __restrict__ smask) {
  int idx = blockIdx.x * 256 + threadIdx.x;
  if (idx < 442368) {                       // wqT[n][k] = wq[k][n]
    int nn = idx / 384, kk = idx % 384;
    wqT[idx] = f2bf(wq[(size_t)kk * 1152 + nn]);
  } else if (idx < 589824) {                // wpT[n][k] = wp[k][n]
    int i2 = idx - 442368;
    int nn = i2 / 384, kk = i2 % 384;
    wpT[i2] = f2bf(wp[(size_t)kk * 384 + nn]);
  } else if (idx < 705072) {                // smask[g][h][n][m]
    int i3 = idx - 589824;
    int g = i3 / 28812;
    int rem = i3 % 28812;
    int h = rem / 2401;
    int nm = rem % 2401;
    smask[i3] = bt[ri[nm] * 12 + h] + mask[g * 2401 + nm];
  }
}

// ---------------- conv_x: fp32 x -> bf16 (one pass) ------------------------
__global__ __launch_bounds__(256) void conv_x(const float* __restrict__ x,
                                              u16* __restrict__ xb) {
  size_t i = ((size_t)blockIdx.x * 256 + threadIdx.x) * 8;
  f32x4 a = *(const f32x4*)(x + i);
  f32x4 b = *(const f32x4*)(x + i + 4);
  u16x8 o;
  o[0] = f2bf(a[0]); o[1] = f2bf(a[1]); o[2] = f2bf(a[2]); o[3] = f2bf(a[3]);
  o[4] = f2bf(b[0]); o[5] = f2bf(b[1]); o[6] = f2bf(b[2]); o[7] = f2bf(b[3]);
  *(u16x8*)(xb + i) = o;
}

// ---------------- GEMM v2: C^T orientation, 2-phase dbuf pipeline ----------
// D[ch][tok] = W[ch][:] . X[tok][:].  A-operand = weights (128 ch tile),
// B-operand = tokens (256 tok tile), BK=64, 8 waves (2ch x 4tok), wave tile
// 64x64, acc 4x4.  LDS double-buffered (96 KB).  T3-minimum schedule:
// stage(next) -> ds_read(cur)+MFMA -> syncthreads (drains prefetched loads
// whose latency hid under compute).  T2 XOR swizzle; T1 XCD chunking.
// Epilogue: lane holds 4 consecutive channels -> vectorized stores.
template <int NCH, bool QKV>
__global__ __launch_bounds__(512) void gemm2(
    const u16* __restrict__ Wt, const u16* __restrict__ Xb,
    const float* __restrict__ bias, void* __restrict__ outp) {
  __shared__ u16 As[2][128 * 64];
  __shared__ u16 Bs[2][256 * 64];
  const int t = threadIdx.x;
  const int l = t & 63, w = t >> 6;

  // XCD-chunked bijective remap (nwg = 784*NCH, divisible by 8):
  const int bid = blockIdx.x;
  const int xcd = bid & 7, q = bid >> 3;
  const int logical = xcd * (98 * NCH) + q;
  const int tokt = logical / NCH, cht = logical % NCH;
  const int tb = tokt * 256;
  const int cb = cht * 128;
  const int LDC = NCH * 128;

  f32x4 acc[4][4];
#pragma unroll
  for (int mi = 0; mi < 4; ++mi)
#pragma unroll
    for (int ni = 0; ni < 4; ++ni) acc[mi][ni] = zf4();

  // fragment read positions
  const int rA = (w >> 2) * 64 + (l & 15);     // channel row in A tile
  const int rB = (w & 3) * 64 + (l & 15);      // token row in B tile
  const int gsel = l >> 4;
  const int xA = rA & 7, xB = rB & 7;
  const int wub = (t & ~63) * 8;               // wave-uniform LDS elem offset

  // stage k-tile kt into buffer bf (A: 2 loads/thr, B: 4 loads/thr)
  auto stage = [&](int bf, int kt) {
    const int ko = kt * 64;
#pragma unroll
    for (int j = 0; j < 2; ++j) {
      const int gi = j * 512 + t;
      const int row = gi >> 3, slot = gi & 7;
      __builtin_amdgcn_global_load_lds(
          (const __attribute__((address_space(1))) unsigned int*)
              (Wt + (size_t)(cb + row) * 384 + ko + ((slot ^ (row & 7)) * 8)),
          (__attribute__((address_space(3))) unsigned int*)(&As[bf][j * 4096 + wub]),
          16, 0, 0);
    }
#pragma unroll
    for (int j = 0; j < 4; ++j) {
      const int gi = j * 512 + t;
      const int row = gi >> 3, slot = gi & 7;
      __builtin_amdgcn_global_load_lds(
          (const __attribute__((address_space(1))) unsigned int*)
              (Xb + (size_t)(tb + row) * 384 + ko + ((slot ^ (row & 7)) * 8)),
          (__attribute__((address_space(3))) unsigned int*)(&Bs[bf][j * 4096 + wub]),
          16, 0, 0);
    }
  };

  stage(0, 0);
  __syncthreads();                 // vmcnt(0) drain of prologue stage

  int cur = 0;
#pragma unroll
  for (int kt = 0; kt < 6; ++kt) {
    if (kt < 5) stage(cur ^ 1, kt + 1);     // prefetch next tile
    __builtin_amdgcn_sched_barrier(0);      // pin stage issue before compute
#pragma unroll
    for (int ks = 0; ks < 2; ++ks) {
      const int gA = ((ks * 4 + gsel) ^ xA) * 8;
      const int gB = ((ks * 4 + gsel) ^ xB) * 8;
      bf16x8 af[4], bfr[4];
#pragma unroll
      for (int mi = 0; mi < 4; ++mi)
        af[mi] = *(const bf16x8*)(&As[cur][(rA + mi * 16) * 64 + gA]);
#pragma unroll
      for (int nj = 0; nj < 4; ++nj)
        bfr[nj] = *(const bf16x8*)(&Bs[cur][(rB + nj * 16) * 64 + gB]);
      __builtin_amdgcn_s_setprio(1);
#pragma unroll
      for (int mi = 0; mi < 4; ++mi)
#pragma unroll
        for (int nj = 0; nj < 4; ++nj)
          acc[mi][nj] = MFMA16(af[mi], bfr[nj], acc[mi][nj], 0, 0, 0);
      __builtin_amdgcn_s_setprio(0);
    }
    __syncthreads();               // drains vmcnt(0): prefetched tile landed
    cur ^= 1;
  }

  // epilogue: lane holds D[ch..ch+3][tok]; ch consecutive -> vector stores
  const int wch = (w >> 2) * 64, wtok = (w & 3) * 64;
#pragma unroll
  for (int mi = 0; mi < 4; ++mi) {
    const int ch = cb + wch + mi * 16 + (l >> 4) * 4;
    const f32x4 bv = *(const f32x4*)(bias + ch);
#pragma unroll
    for (int nj = 0; nj < 4; ++nj) {
      const int tok = tb + wtok + nj * 16 + (l & 15);
      if constexpr (QKV) {
        const float scl = (ch < 384) ? QSCALE : 1.0f;
        u16x4 pk;
#pragma unroll
        for (int r = 0; r < 4; ++r) pk[r] = f2bf((acc[mi][nj][r] + bv[r]) * scl);
        *(u16x4*)((u16*)outp + (size_t)tok * LDC + ch) = pk;
      } else {
        f32x4 o;
#pragma unroll
        for (int r = 0; r < 4; ++r) o[r] = acc[mi][nj][r] + bv[r];
        *(f32x4*)((float*)outp + (size_t)tok * LDC + ch) = o;
      }
    }
  }
}

// ---------------- Attention: per-window, per-head -------------------------
// PV computed as O^T = V^T @ P^T (A = V^T frags from transposed-V LDS,
// B = P^T frags == row-major P b128 reads). No tr_read instructions.
__global__ __launch_bounds__(256) void attn_kernel(
    const u16* __restrict__ qkvb, const float* __restrict__ smask,
    u16* __restrict__ attnb) {
  __shared__ u16 Pl[4][64 * 72];   // P per wave: [n][k], stride 72 u16
  __shared__ u16 Vt[4][2336];      // V^T per wave: [d][k], addr d*72+(d>>3)*8+k
  const int t = threadIdx.x;
  const int l = t & 63, w = t >> 6;
  const int b = blockIdx.x;
  u16* Pw = &Pl[w][0];
  u16* Vw = &Vt[w][0];

  for (int hi = 0; hi < 3; ++hi) {
    const int h = w + hi * 4;
    const u16* base = qkvb + (size_t)b * 49 * 1152 + h * 32 + (l >> 4) * 8;

    // V^T staging: load V[row][sg*8..+8] (zero for row>=49), scatter to [d][k]
#pragma unroll
    for (int i = 0; i < 4; ++i) {
      const int row = i * 16 + (l >> 2);
      const int sg = l & 3;
      u16x8 vv = {0, 0, 0, 0, 0, 0, 0, 0};
      if (row < 49)
        vv = *(const u16x8*)(qkvb + (size_t)(b * 49 + row) * 1152 + 768 + h * 32 + sg * 8);
#pragma unroll
      for (int e = 0; e < 8; ++e) {
        const int d = sg * 8 + e;
        Vw[d * 72 + (d >> 3) * 8 + row] = vv[e];
      }
    }

    // q (A-frag) / k (B-frag) from global
    bf16x8 qa[4], kb[4];
#pragma unroll
    for (int mi = 0; mi < 4; ++mi) {
      const int n = mi * 16 + (l & 15);
      u16x8 z = {0, 0, 0, 0, 0, 0, 0, 0};
      qa[mi] = (n < 49) ? *(const bf16x8*)(base + (size_t)n * 1152) : as_bf(z);
    }
#pragma unroll
    for (int nj = 0; nj < 4; ++nj) {
      const int m = nj * 16 + (l & 15);
      u16x8 z = {0, 0, 0, 0, 0, 0, 0, 0};
      kb[nj] = (m < 49) ? *(const bf16x8*)(base + 384 + (size_t)m * 1152) : as_bf(z);
    }

    // S = q k^T
    f32x4 s[4][4];
    __builtin_amdgcn_s_setprio(1);
#pragma unroll
    for (int mi = 0; mi < 4; ++mi)
#pragma unroll
      for (int nj = 0; nj < 4; ++nj) s[mi][nj] = MFMA16(qa[mi], kb[nj], zf4(), 0, 0, 0);
    __builtin_amdgcn_s_setprio(0);

    // bias + shift mask
    const float* sm = smask + ((size_t)(b & 3) * 12 + h) * 2401;
#pragma unroll
    for (int mi = 0; mi < 4; ++mi) {
#pragma unroll
      for (int r = 0; r < 4; ++r) {
        const int n = mi * 16 + (l >> 4) * 4 + r;
        if (n < 49) {
#pragma unroll
          for (int nj = 0; nj < 4; ++nj) {
            const int m = nj * 16 + (l & 15);
            s[mi][nj][r] = (m < 49) ? s[mi][nj][r] + sm[n * 49 + m] : -1e30f;
          }
        }
      }
    }
    // softmax: per-row reduce over 4 local cols + 16 lanes (DPP, VALU-only)
#pragma unroll
    for (int mi = 0; mi < 4; ++mi) {
#pragma unroll
      for (int r = 0; r < 4; ++r) {
        float mx = fmaxf(fmaxf(s[mi][0][r], s[mi][1][r]), fmaxf(s[mi][2][r], s[mi][3][r]));
        mx = rmax16(mx);
        float e0 = 0.f;
#pragma unroll
        for (int nj = 0; nj < 4; ++nj) {
          const float p = __expf(s[mi][nj][r] - mx);
          s[mi][nj][r] = p;
          e0 += p;
        }
        e0 = rsum16(e0);
        const float inv = 1.0f / e0;
#pragma unroll
        for (int nj = 0; nj < 4; ++nj) s[mi][nj][r] *= inv;
      }
    }
    // P -> LDS bf16 ([n][k], stride 72)
#pragma unroll
    for (int mi = 0; mi < 4; ++mi)
#pragma unroll
      for (int r = 0; r < 4; ++r) {
        const int row = mi * 16 + (l >> 4) * 4 + r;
#pragma unroll
        for (int nj = 0; nj < 4; ++nj)
          Pw[row * 72 + nj * 16 + (l & 15)] = f2bf(s[mi][nj][r]);
      }
    // drain wave-local LDS writes (V^T + P); waves own disjoint regions
    asm volatile("s_waitcnt lgkmcnt(0)" ::: "memory");
    __builtin_amdgcn_sched_barrier(0);

    // O^T[d][n] = sum_k V^T[d][k] P^T[k][n]
    f32x4 ot[2][4];
#pragma unroll
    for (int dj = 0; dj < 2; ++dj)
#pragma unroll
      for (int mi = 0; mi < 4; ++mi) ot[dj][mi] = zf4();
#pragma unroll
    for (int ks = 0; ks < 2; ++ks) {
      bf16x8 va[2], pb[4];
#pragma unroll
      for (int dj = 0; dj < 2; ++dj) {
        const int d0 = dj * 16 + (l & 15);
        va[dj] = *(const bf16x8*)(Vw + d0 * 72 + (d0 >> 3) * 8 + ks * 32 + (l >> 4) * 8);
      }
#pragma unroll
      for (int mi = 0; mi < 4; ++mi)
        pb[mi] = *(const bf16x8*)(Pw + (mi * 16 + (l & 15)) * 72 + ks * 32 + (l >> 4) * 8);
      __builtin_amdgcn_s_setprio(1);
#pragma unroll
      for (int dj = 0; dj < 2; ++dj)
#pragma unroll
        for (int mi = 0; mi < 4; ++mi)
          ot[dj][mi] = MFMA16(va[dj], pb[mi], ot[dj][mi], 0, 0, 0);
      __builtin_amdgcn_s_setprio(0);
    }
    // store: lane holds O^T[d = dj*16+(l>>4)*4+r][n = mi*16+(l&15)]
#pragma unroll
    for (int dj = 0; dj < 2; ++dj)
#pragma unroll
      for (int mi = 0; mi < 4; ++mi) {
        const int n = mi * 16 + (l & 15);
        if (n < 49) {
          u16x4 pk;
          pk[0] = f2bf(ot[dj][mi][0]);
          pk[1] = f2bf(ot[dj][mi][1]);
          pk[2] = f2bf(ot[dj][mi][2]);
          pk[3] = f2bf(ot[dj][mi][3]);
          *(u16x4*)(attnb + (size_t)(b * 49 + n) * 384 + h * 32 + dj * 16 + (l >> 4) * 4) = pk;
        }
      }
    // all LDS reads of this iter retired before next iter overwrites
    asm volatile("s_waitcnt lgkmcnt(0)" ::: "memory");
    __builtin_amdgcn_sched_barrier(0);
  }
}

extern "C" void kernel_launch(void* const* d_in, const int* in_sizes, int n_in,
                              void* d_out, int out_size, void* d_ws, size_t ws_size,
                              hipStream_t stream) {
  const float* x       = (const float*)d_in[0];
  const float* mask    = (const float*)d_in[1];
  const float* w_qkv   = (const float*)d_in[2];
  const float* b_qkv   = (const float*)d_in[3];
  const float* bias_t  = (const float*)d_in[4];
  const float* w_proj  = (const float*)d_in[5];
  const float* b_proj  = (const float*)d_in[6];
  const int*   rel_idx = (const int*)d_in[7];
  float* out = (float*)d_out;

  char* ws = (char*)d_ws;
  u16*   wqT   = (u16*)ws;                       // 442368 u16
  u16*   wpT   = (u16*)(ws + 884736);            // 147456 u16
  float* smask = (float*)(ws + 1179648);         // 115248 f32
  u16*   qkvb  = (u16*)(ws + 1640640);           // 200704*1152 u16
  u16*   xb    = (u16*)(ws + 464062656);         // 200704*384 u16 (aliases attnb)
  u16*   attnb = (u16*)(ws + 464062656);         // xb dead before attn writes

  prep_kernel<<<2755, 256, 0, stream>>>(w_qkv, w_proj, bias_t, rel_idx, mask,
                                        wqT, wpT, smask);
  conv_x<<<37632, 256, 0, stream>>>(x, xb);
  gemm2<9, true><<<7056, 512, 0, stream>>>(wqT, xb, b_qkv, qkvb);
  attn_kernel<<<4096, 256, 0, stream>>>(qkvb, smask, attnb);
  gemm2<3, false><<<2352, 512, 0, stream>>>(wpT, attnb, b_proj, out);
}

// Round 5
// 887.634 us; speedup vs baseline: 1.1133x; 1.1133x over previous
//
#include <hip/hip_runtime.h>

typedef unsigned short u16;
typedef u16 u16x4 __attribute__((ext_vector_type(4)));
typedef u16 u16x8 __attribute__((ext_vector_type(8)));
typedef __bf16 bf16x8 __attribute__((ext_vector_type(8)));
typedef float f32x4 __attribute__((ext_vector_type(4)));

#define MFMA16 __builtin_amdgcn_mfma_f32_16x16x32_bf16
#define QSCALE 0.17677669529663689f

__device__ __forceinline__ u16 f2bf(float f) {
  unsigned u = __builtin_bit_cast(unsigned, f);
  u += 0x7fffu + ((u >> 16) & 1u);
  return (u16)(u >> 16);
}
__device__ __forceinline__ bf16x8 as_bf(u16x8 u) { return __builtin_bit_cast(bf16x8, u); }
__device__ __forceinline__ f32x4 zf4() { f32x4 z = {0.f, 0.f, 0.f, 0.f}; return z; }

// DPP lane permute (VALU, no LDS pipe). Reductions over the 16-lane row.
template <int CTRL>
__device__ __forceinline__ float dppf(float x) {
  int i = __builtin_bit_cast(int, x);
  int r = __builtin_amdgcn_update_dpp(i, i, CTRL, 0xf, 0xf, false);
  return __builtin_bit_cast(float, r);
}
__device__ __forceinline__ float rmax16(float x) {
  x = fmaxf(x, dppf<0xB1>(x));    // quad_perm xor1
  x = fmaxf(x, dppf<0x4E>(x));    // quad_perm xor2
  x = fmaxf(x, dppf<0x124>(x));   // row_ror:4
  x = fmaxf(x, dppf<0x128>(x));   // row_ror:8
  return x;
}
__device__ __forceinline__ float rsum16(float x) {
  x += dppf<0xB1>(x);
  x += dppf<0x4E>(x);
  x += dppf<0x124>(x);
  x += dppf<0x128>(x);
  return x;
}

// ---------------- prep: weight transpose->bf16, smask build ----------------
__global__ __launch_bounds__(256) void prep_kernel(
    const float* __restrict__ wq, const float* __restrict__ wp,
    const float* __restrict__ bt, const int* __restrict__ ri,
    const float* __restrict__ mask,
    u16* __restrict__ wqT, u16* __restrict__ wpT, float* __restrict__ smask) {
  int idx = blockIdx.x * 256 + threadIdx.x;
  if (idx < 442368) {                       // wqT[n][k] = wq[k][n]
    int nn = idx / 384, kk = idx % 384;
    wqT[idx] = f2bf(wq[(size_t)kk * 1152 + nn]);
  } else if (idx < 589824) {                // wpT[n][k] = wp[k][n]
    int i2 = idx - 442368;
    int nn = i2 / 384, kk = i2 % 384;
    wpT[i2] = f2bf(wp[(size_t)kk * 384 + nn]);
  } else if (idx < 705072) {                // smask[g][h][n][m]
    int i3 = idx - 589824;
    int g = i3 / 28812;
    int rem = i3 % 28812;
    int h = rem / 2401;
    int nm = rem % 2401;
    smask[i3] = bt[ri[nm] * 12 + h] + mask[g * 2401 + nm];
  }
}

// ---------------- conv_x: fp32 x -> bf16 (one pass) ------------------------
__global__ __launch_bounds__(256) void conv_x(const float* __restrict__ x,
                                              u16* __restrict__ xb) {
  size_t i = ((size_t)blockIdx.x * 256 + threadIdx.x) * 8;
  f32x4 a = *(const f32x4*)(x + i);
  f32x4 b = *(const f32x4*)(x + i + 4);
  u16x8 o;
  o[0] = f2bf(a[0]); o[1] = f2bf(a[1]); o[2] = f2bf(a[2]); o[3] = f2bf(a[3]);
  o[4] = f2bf(b[0]); o[5] = f2bf(b[1]); o[6] = f2bf(b[2]); o[7] = f2bf(b[3]);
  *(u16x8*)(xb + i) = o;
}

// ---------------- GEMM v3: C^T orientation, BK=32, high occupancy ----------
// D[ch][tok] = W[ch][:] . X[tok][:].  128ch x 128tok tile, BK=32, 4 waves
// (2x2), wave 64x64, acc 4x4.  Double-buffered LDS = 32 KB/block -> ~5
// blocks/CU (20 waves) so inter-block TLP hides staging latency; 1-deep
// prefetch adds intra-block overlap.  T2 swizzle (4 granules/row, XOR
// (row>>1)&3, <=2-way which is free); T1 XCD chunking.
template <int NCH, bool QKV>
__global__ __launch_bounds__(256) void gemm3(
    const u16* __restrict__ Wt, const u16* __restrict__ Xb,
    const float* __restrict__ bias, void* __restrict__ outp) {
  __shared__ u16 As[2][128 * 32];
  __shared__ u16 Bs[2][128 * 32];
  const int t = threadIdx.x;
  const int l = t & 63, w = t >> 6;

  // XCD-chunked bijective remap: nwg = 1568*NCH, divisible by 8.
  const int bid = blockIdx.x;
  const int xcd = bid & 7, q = bid >> 3;
  const int logical = xcd * (196 * NCH) + q;
  const int tokt = logical / NCH, cht = logical % NCH;
  const int tb = tokt * 128;
  const int cb = cht * 128;
  const int LDC = NCH * 128;

  f32x4 acc[4][4];
#pragma unroll
  for (int mi = 0; mi < 4; ++mi)
#pragma unroll
    for (int ni = 0; ni < 4; ++ni) acc[mi][ni] = zf4();

  // fragment read positions
  const int rA = (w >> 1) * 64 + (l & 15);     // channel row in A tile
  const int rB = (w & 1) * 64 + (l & 15);      // token row in B tile
  const int gsel = l >> 4;
  const int gA = ((gsel ^ ((rA >> 1) & 3))) * 8;
  const int gB = ((gsel ^ ((rB >> 1) & 3))) * 8;

  // stage k-tile kt into buffer bf: A 2 chunks/thr + B 2 chunks/thr
  auto stage = [&](int bf, int kt) {
    const int ko = kt * 32;
#pragma unroll
    for (int j = 0; j < 2; ++j) {
      const int gi = j * 256 + t;            // 0..511
      const int row = gi >> 2, slot = gi & 3;
      const int sg = (slot ^ ((row >> 1) & 3)) * 8;
      __builtin_amdgcn_global_load_lds(
          (const __attribute__((address_space(1))) unsigned int*)
              (Wt + (size_t)(cb + row) * 384 + ko + sg),
          (__attribute__((address_space(3))) unsigned int*)(&As[bf][gi * 8]),
          16, 0, 0);
      __builtin_amdgcn_global_load_lds(
          (const __attribute__((address_space(1))) unsigned int*)
              (Xb + (size_t)(tb + row) * 384 + ko + sg),
          (__attribute__((address_space(3))) unsigned int*)(&Bs[bf][gi * 8]),
          16, 0, 0);
    }
  };

  stage(0, 0);
  __syncthreads();                 // prologue drain

  int cur = 0;
#pragma unroll
  for (int kt = 0; kt < 12; ++kt) {
    if (kt < 11) stage(cur ^ 1, kt + 1);    // prefetch next k-tile
    __builtin_amdgcn_sched_barrier(0);      // keep stage issue ahead of compute
    bf16x8 af[4], bfr[4];
#pragma unroll
    for (int mi = 0; mi < 4; ++mi)
      af[mi] = *(const bf16x8*)(&As[cur][(rA + mi * 16) * 32 + gA]);
#pragma unroll
    for (int nj = 0; nj < 4; ++nj)
      bfr[nj] = *(const bf16x8*)(&Bs[cur][(rB + nj * 16) * 32 + gB]);
    __builtin_amdgcn_s_setprio(1);
#pragma unroll
    for (int mi = 0; mi < 4; ++mi)
#pragma unroll
      for (int nj = 0; nj < 4; ++nj)
        acc[mi][nj] = MFMA16(af[mi], bfr[nj], acc[mi][nj], 0, 0, 0);
    __builtin_amdgcn_s_setprio(0);
    __syncthreads();               // drains vmcnt: prefetched tile landed
    cur ^= 1;
  }

  // epilogue: lane holds D[ch..ch+3][tok]; ch consecutive -> vector stores
#pragma unroll
  for (int mi = 0; mi < 4; ++mi) {
    const int ch = cb + (w >> 1) * 64 + mi * 16 + (l >> 4) * 4;
    const f32x4 bv = *(const f32x4*)(bias + ch);
#pragma unroll
    for (int nj = 0; nj < 4; ++nj) {
      const int tok = tb + (w & 1) * 64 + nj * 16 + (l & 15);
      if constexpr (QKV) {
        const float scl = (ch < 384) ? QSCALE : 1.0f;
        u16x4 pk;
#pragma unroll
        for (int r = 0; r < 4; ++r) pk[r] = f2bf((acc[mi][nj][r] + bv[r]) * scl);
        *(u16x4*)((u16*)outp + (size_t)tok * LDC + ch) = pk;
      } else {
        f32x4 o;
#pragma unroll
        for (int r = 0; r < 4; ++r) o[r] = acc[mi][nj][r] + bv[r];
        *(f32x4*)((float*)outp + (size_t)tok * LDC + ch) = o;
      }
    }
  }
}

// ---------------- Attention: per-window, per-head -------------------------
// PV computed as O^T = V^T @ P^T (A = V^T frags from transposed-V LDS,
// B = P^T frags == row-major P b128 reads). No tr_read instructions.
__global__ __launch_bounds__(256) void attn_kernel(
    const u16* __restrict__ qkvb, const float* __restrict__ smask,
    u16* __restrict__ attnb) {
  __shared__ u16 Pl[4][64 * 72];   // P per wave: [n][k], stride 72 u16
  __shared__ u16 Vt[4][2336];      // V^T per wave: [d][k], addr d*72+(d>>3)*8+k
  const int t = threadIdx.x;
  const int l = t & 63, w = t >> 6;
  const int b = blockIdx.x;
  u16* Pw = &Pl[w][0];
  u16* Vw = &Vt[w][0];

  for (int hi = 0; hi < 3; ++hi) {
    const int h = w + hi * 4;
    const u16* base = qkvb + (size_t)b * 49 * 1152 + h * 32 + (l >> 4) * 8;

    // V^T staging: load V[row][sg*8..+8] (zero for row>=49), scatter to [d][k]
#pragma unroll
    for (int i = 0; i < 4; ++i) {
      const int row = i * 16 + (l >> 2);
      const int sg = l & 3;
      u16x8 vv = {0, 0, 0, 0, 0, 0, 0, 0};
      if (row < 49)
        vv = *(const u16x8*)(qkvb + (size_t)(b * 49 + row) * 1152 + 768 + h * 32 + sg * 8);
#pragma unroll
      for (int e = 0; e < 8; ++e) {
        const int d = sg * 8 + e;
        Vw[d * 72 + (d >> 3) * 8 + row] = vv[e];
      }
    }

    // q (A-frag) / k (B-frag) from global
    bf16x8 qa[4], kb[4];
#pragma unroll
    for (int mi = 0; mi < 4; ++mi) {
      const int n = mi * 16 + (l & 15);
      u16x8 z = {0, 0, 0, 0, 0, 0, 0, 0};
      qa[mi] = (n < 49) ? *(const bf16x8*)(base + (size_t)n * 1152) : as_bf(z);
    }
#pragma unroll
    for (int nj = 0; nj < 4; ++nj) {
      const int m = nj * 16 + (l & 15);
      u16x8 z = {0, 0, 0, 0, 0, 0, 0, 0};
      kb[nj] = (m < 49) ? *(const bf16x8*)(base + 384 + (size_t)m * 1152) : as_bf(z);
    }

    // S = q k^T
    f32x4 s[4][4];
    __builtin_amdgcn_s_setprio(1);
#pragma unroll
    for (int mi = 0; mi < 4; ++mi)
#pragma unroll
      for (int nj = 0; nj < 4; ++nj) s[mi][nj] = MFMA16(qa[mi], kb[nj], zf4(), 0, 0, 0);
    __builtin_amdgcn_s_setprio(0);

    // bias + shift mask
    const float* sm = smask + ((size_t)(b & 3) * 12 + h) * 2401;
#pragma unroll
    for (int mi = 0; mi < 4; ++mi) {
#pragma unroll
      for (int r = 0; r < 4; ++r) {
        const int n = mi * 16 + (l >> 4) * 4 + r;
        if (n < 49) {
#pragma unroll
          for (int nj = 0; nj < 4; ++nj) {
            const int m = nj * 16 + (l & 15);
            s[mi][nj][r] = (m < 49) ? s[mi][nj][r] + sm[n * 49 + m] : -1e30f;
          }
        }
      }
    }
    // softmax: per-row reduce over 4 local cols + 16 lanes (DPP, VALU-only)
#pragma unroll
    for (int mi = 0; mi < 4; ++mi) {
#pragma unroll
      for (int r = 0; r < 4; ++r) {
        float mx = fmaxf(fmaxf(s[mi][0][r], s[mi][1][r]), fmaxf(s[mi][2][r], s[mi][3][r]));
        mx = rmax16(mx);
        float e0 = 0.f;
#pragma unroll
        for (int nj = 0; nj < 4; ++nj) {
          const float p = __expf(s[mi][nj][r] - mx);
          s[mi][nj][r] = p;
          e0 += p;
        }
        e0 = rsum16(e0);
        const float inv = 1.0f / e0;
#pragma unroll
        for (int nj = 0; nj < 4; ++nj) s[mi][nj][r] *= inv;
      }
    }
    // P -> LDS bf16 ([n][k], stride 72)
#pragma unroll
    for (int mi = 0; mi < 4; ++mi)
#pragma unroll
      for (int r = 0; r < 4; ++r) {
        const int row = mi * 16 + (l >> 4) * 4 + r;
#pragma unroll
        for (int nj = 0; nj < 4; ++nj)
          Pw[row * 72 + nj * 16 + (l & 15)] = f2bf(s[mi][nj][r]);
      }
    // drain wave-local LDS writes (V^T + P); waves own disjoint regions
    asm volatile("s_waitcnt lgkmcnt(0)" ::: "memory");
    __builtin_amdgcn_sched_barrier(0);

    // O^T[d][n] = sum_k V^T[d][k] P^T[k][n]
    f32x4 ot[2][4];
#pragma unroll
    for (int dj = 0; dj < 2; ++dj)
#pragma unroll
      for (int mi = 0; mi < 4; ++mi) ot[dj][mi] = zf4();
#pragma unroll
    for (int ks = 0; ks < 2; ++ks) {
      bf16x8 va[2], pb[4];
#pragma unroll
      for (int dj = 0; dj < 2; ++dj) {
        const int d0 = dj * 16 + (l & 15);
        va[dj] = *(const bf16x8*)(Vw + d0 * 72 + (d0 >> 3) * 8 + ks * 32 + (l >> 4) * 8);
      }
#pragma unroll
      for (int mi = 0; mi < 4; ++mi)
        pb[mi] = *(const bf16x8*)(Pw + (mi * 16 + (l & 15)) * 72 + ks * 32 + (l >> 4) * 8);
      __builtin_amdgcn_s_setprio(1);
#pragma unroll
      for (int dj = 0; dj < 2; ++dj)
#pragma unroll
        for (int mi = 0; mi < 4; ++mi)
          ot[dj][mi] = MFMA16(va[dj], pb[mi], ot[dj][mi], 0, 0, 0);
      __builtin_amdgcn_s_setprio(0);
    }
    // store: lane holds O^T[d = dj*16+(l>>4)*4+r][n = mi*16+(l&15)]
#pragma unroll
    for (int dj = 0; dj < 2; ++dj)
#pragma unroll
      for (int mi = 0; mi < 4; ++mi) {
        const int n = mi * 16 + (l & 15);
        if (n < 49) {
          u16x4 pk;
          pk[0] = f2bf(ot[dj][mi][0]);
          pk[1] = f2bf(ot[dj][mi][1]);
          pk[2] = f2bf(ot[dj][mi][2]);
          pk[3] = f2bf(ot[dj][mi][3]);
          *(u16x4*)(attnb + (size_t)(b * 49 + n) * 384 + h * 32 + dj * 16 + (l >> 4) * 4) = pk;
        }
      }
    // all LDS reads of this iter retired before next iter overwrites
    asm volatile("s_waitcnt lgkmcnt(0)" ::: "memory");
    __builtin_amdgcn_sched_barrier(0);
  }
}

extern "C" void kernel_launch(void* const* d_in, const int* in_sizes, int n_in,
                              void* d_out, int out_size, void* d_ws, size_t ws_size,
                              hipStream_t stream) {
  const float* x       = (const float*)d_in[0];
  const float* mask    = (const float*)d_in[1];
  const float* w_qkv   = (const float*)d_in[2];
  const float* b_qkv   = (const float*)d_in[3];
  const float* bias_t  = (const float*)d_in[4];
  const float* w_proj  = (const float*)d_in[5];
  const float* b_proj  = (const float*)d_in[6];
  const int*   rel_idx = (const int*)d_in[7];
  float* out = (float*)d_out;

  char* ws = (char*)d_ws;
  u16*   wqT   = (u16*)ws;                       // 442368 u16
  u16*   wpT   = (u16*)(ws + 884736);            // 147456 u16
  float* smask = (float*)(ws + 1179648);         // 115248 f32
  u16*   qkvb  = (u16*)(ws + 1640640);           // 200704*1152 u16
  u16*   xb    = (u16*)(ws + 464062656);         // 200704*384 u16 (aliases attnb)
  u16*   attnb = (u16*)(ws + 464062656);         // xb dead before attn writes

  prep_kernel<<<2755, 256, 0, stream>>>(w_qkv, w_proj, bias_t, rel_idx, mask,
                                        wqT, wpT, smask);
  conv_x<<<37632, 256, 0, stream>>>(x, xb);
  gemm3<9, true><<<14112, 256, 0, stream>>>(wqT, xb, b_qkv, qkvb);
  attn_kernel<<<4096, 256, 0, stream>>>(qkvb, smask, attnb);
  gemm3<3, false><<<4704, 256, 0, stream>>>(wpT, attnb, b_proj, out);
}

// Round 6
// 877.376 us; speedup vs baseline: 1.1264x; 1.0117x over previous
//
#include <hip/hip_runtime.h>

typedef unsigned short u16;
typedef u16 u16x4 __attribute__((ext_vector_type(4)));
typedef u16 u16x8 __attribute__((ext_vector_type(8)));
typedef __bf16 bf16x8 __attribute__((ext_vector_type(8)));
typedef float f32x4 __attribute__((ext_vector_type(4)));

#define MFMA16 __builtin_amdgcn_mfma_f32_16x16x32_bf16
#define QSCALE 0.17677669529663689f
#define VMWAIT(N) asm volatile("s_waitcnt vmcnt(" #N ")" ::: "memory")

__device__ __forceinline__ u16 f2bf(float f) {
  unsigned u = __builtin_bit_cast(unsigned, f);
  u += 0x7fffu + ((u >> 16) & 1u);
  return (u16)(u >> 16);
}
__device__ __forceinline__ bf16x8 as_bf(u16x8 u) { return __builtin_bit_cast(bf16x8, u); }
__device__ __forceinline__ f32x4 zf4() { f32x4 z = {0.f, 0.f, 0.f, 0.f}; return z; }

// DPP lane permute (VALU, no LDS pipe). Reductions over the 16-lane row.
template <int CTRL>
__device__ __forceinline__ float dppf(float x) {
  int i = __builtin_bit_cast(int, x);
  int r = __builtin_amdgcn_update_dpp(i, i, CTRL, 0xf, 0xf, false);
  return __builtin_bit_cast(float, r);
}
__device__ __forceinline__ float rmax16(float x) {
  x = fmaxf(x, dppf<0xB1>(x));    // quad_perm xor1
  x = fmaxf(x, dppf<0x4E>(x));    // quad_perm xor2
  x = fmaxf(x, dppf<0x124>(x));   // row_ror:4
  x = fmaxf(x, dppf<0x128>(x));   // row_ror:8
  return x;
}
__device__ __forceinline__ float rsum16(float x) {
  x += dppf<0xB1>(x);
  x += dppf<0x4E>(x);
  x += dppf<0x124>(x);
  x += dppf<0x128>(x);
  return x;
}

// ---------------- prep: weight transpose->bf16, smask build ----------------
__global__ __launch_bounds__(256) void prep_kernel(
    const float* __restrict__ wq, const float* __restrict__ wp,
    const float* __restrict__ bt, const int* __restrict__ ri,
    const float* __restrict__ mask,
    u16* __restrict__ wqT, u16* __restrict__ wpT, float* __restrict__ smask) {
  int idx = blockIdx.x * 256 + threadIdx.x;
  if (idx < 442368) {                       // wqT[n][k] = wq[k][n]
    int nn = idx / 384, kk = idx % 384;
    wqT[idx] = f2bf(wq[(size_t)kk * 1152 + nn]);
  } else if (idx < 589824) {                // wpT[n][k] = wp[k][n]
    int i2 = idx - 442368;
    int nn = i2 / 384, kk = i2 % 384;
    wpT[i2] = f2bf(wp[(size_t)kk * 384 + nn]);
  } else if (idx < 705072) {                // smask[g][h][n][m]
    int i3 = idx - 589824;
    int g = i3 / 28812;
    int rem = i3 % 28812;
    int h = rem / 2401;
    int nm = rem % 2401;
    smask[i3] = bt[ri[nm] * 12 + h] + mask[g * 2401 + nm];
  }
}

// ---------------- conv_x: fp32 x -> bf16 (one pass) ------------------------
__global__ __launch_bounds__(256) void conv_x(const float* __restrict__ x,
                                              u16* __restrict__ xb) {
  size_t i = ((size_t)blockIdx.x * 256 + threadIdx.x) * 8;
  f32x4 a = *(const f32x4*)(x + i);
  f32x4 b = *(const f32x4*)(x + i + 4);
  u16x8 o;
  o[0] = f2bf(a[0]); o[1] = f2bf(a[1]); o[2] = f2bf(a[2]); o[3] = f2bf(a[3]);
  o[4] = f2bf(b[0]); o[5] = f2bf(b[1]); o[6] = f2bf(b[2]); o[7] = f2bf(b[3]);
  *(u16x8*)(xb + i) = o;
}

// ---------------- GEMM v4: C^T, BK=32, counted-vmcnt pipeline --------------
// Same geometry as verified v3 (128x128, 4 waves, dbuf 32KB, T2 swizzle,
// T1 XCD chunking).  K-loop sync skeleton replaced with the T3/T4 pattern:
// per step {vmcnt(4) -> s_barrier -> ds_read(cur) -> lgkmcnt(0) ->
// s_barrier -> stage(cur, kt+2) -> MFMA}.  Loads stay in flight across
// barriers (never drain to 0 in the main loop); each tile's loads get ~2
// iterations of compute to land.
template <int NCH, bool QKV>
__global__ __launch_bounds__(256) void gemm4(
    const u16* __restrict__ Wt, const u16* __restrict__ Xb,
    const float* __restrict__ bias, void* __restrict__ outp) {
  __shared__ u16 As[2][128 * 32];
  __shared__ u16 Bs[2][128 * 32];
  const int t = threadIdx.x;
  const int l = t & 63, w = t >> 6;

  // XCD-chunked bijective remap: nwg = 1568*NCH, divisible by 8.
  const int bid = blockIdx.x;
  const int xcd = bid & 7, q = bid >> 3;
  const int logical = xcd * (196 * NCH) + q;
  const int tokt = logical / NCH, cht = logical % NCH;
  const int tb = tokt * 128;
  const int cb = cht * 128;
  const int LDC = NCH * 128;

  f32x4 acc[4][4];
#pragma unroll
  for (int mi = 0; mi < 4; ++mi)
#pragma unroll
    for (int ni = 0; ni < 4; ++ni) acc[mi][ni] = zf4();

  // fragment read positions
  const int rA = (w >> 1) * 64 + (l & 15);     // channel row in A tile
  const int rB = (w & 1) * 64 + (l & 15);      // token row in B tile
  const int gsel = l >> 4;
  const int gA = ((gsel ^ ((rA >> 1) & 3))) * 8;
  const int gB = ((gsel ^ ((rB >> 1) & 3))) * 8;

  // stage k-tile kt into buffer bf: 4 global_load_lds per thread
  auto stage = [&](int bf, int kt) {
    const int ko = kt * 32;
#pragma unroll
    for (int j = 0; j < 2; ++j) {
      const int gi = j * 256 + t;            // 0..511
      const int row = gi >> 2, slot = gi & 3;
      const int sg = (slot ^ ((row >> 1) & 3)) * 8;
      __builtin_amdgcn_global_load_lds(
          (const __attribute__((address_space(1))) unsigned int*)
              (Wt + (size_t)(cb + row) * 384 + ko + sg),
          (__attribute__((address_space(3))) unsigned int*)(&As[bf][gi * 8]),
          16, 0, 0);
      __builtin_amdgcn_global_load_lds(
          (const __attribute__((address_space(1))) unsigned int*)
              (Xb + (size_t)(tb + row) * 384 + ko + sg),
          (__attribute__((address_space(3))) unsigned int*)(&Bs[bf][gi * 8]),
          16, 0, 0);
    }
  };

  // one K-step; caller has already done the vmcnt wait for buffer `cur`
  auto kbody = [&](int cur, int ktnext, bool dostage) {
    __builtin_amdgcn_sched_barrier(0);
    __builtin_amdgcn_s_barrier();            // all waves' tile-cur loads landed
    bf16x8 af[4], bfr[4];
#pragma unroll
    for (int mi = 0; mi < 4; ++mi)
      af[mi] = *(const bf16x8*)(&As[cur][(rA + mi * 16) * 32 + gA]);
#pragma unroll
    for (int nj = 0; nj < 4; ++nj)
      bfr[nj] = *(const bf16x8*)(&Bs[cur][(rB + nj * 16) * 32 + gB]);
    asm volatile("s_waitcnt lgkmcnt(0)" ::: "memory");
    __builtin_amdgcn_sched_barrier(0);
    __builtin_amdgcn_s_barrier();            // all reads of cur retired
    if (dostage) stage(cur, ktnext);         // overwrite cur with tile kt+2
    __builtin_amdgcn_sched_barrier(0);
    __builtin_amdgcn_s_setprio(1);
#pragma unroll
    for (int mi = 0; mi < 4; ++mi)
#pragma unroll
      for (int nj = 0; nj < 4; ++nj)
        acc[mi][nj] = MFMA16(af[mi], bfr[nj], acc[mi][nj], 0, 0, 0);
    __builtin_amdgcn_s_setprio(0);
  };

  stage(0, 0);                               // tiles 0 and 1 in flight
  stage(1, 1);
#pragma unroll
  for (int kt = 0; kt < 10; ++kt) {
    VMWAIT(4);                               // tile kt landed; kt+1 in flight
    kbody(kt & 1, kt + 2, true);
  }
  VMWAIT(4);                                 // tile 10 landed; 11 in flight
  kbody(0, 0, false);
  VMWAIT(0);                                 // tile 11 landed
  kbody(1, 0, false);

  // epilogue: lane holds D[ch..ch+3][tok]; ch consecutive -> vector stores
#pragma unroll
  for (int mi = 0; mi < 4; ++mi) {
    const int ch = cb + (w >> 1) * 64 + mi * 16 + (l >> 4) * 4;
    const f32x4 bv = *(const f32x4*)(bias + ch);
#pragma unroll
    for (int nj = 0; nj < 4; ++nj) {
      const int tok = tb + (w & 1) * 64 + nj * 16 + (l & 15);
      if constexpr (QKV) {
        const float scl = (ch < 384) ? QSCALE : 1.0f;
        u16x4 pk;
#pragma unroll
        for (int r = 0; r < 4; ++r) pk[r] = f2bf((acc[mi][nj][r] + bv[r]) * scl);
        *(u16x4*)((u16*)outp + (size_t)tok * LDC + ch) = pk;
      } else {
        f32x4 o;
#pragma unroll
        for (int r = 0; r < 4; ++r) o[r] = acc[mi][nj][r] + bv[r];
        *(f32x4*)((float*)outp + (size_t)tok * LDC + ch) = o;
      }
    }
  }
}

// ---------------- Attention: per-window, per-head -------------------------
// PV computed as O^T = V^T @ P^T (A = V^T frags from transposed-V LDS,
// B = P^T frags == row-major P b128 reads). No tr_read instructions.
__global__ __launch_bounds__(256) void attn_kernel(
    const u16* __restrict__ qkvb, const float* __restrict__ smask,
    u16* __restrict__ attnb) {
  __shared__ u16 Pl[4][64 * 72];   // P per wave: [n][k], stride 72 u16
  __shared__ u16 Vt[4][2336];      // V^T per wave: [d][k], addr d*72+(d>>3)*8+k
  const int t = threadIdx.x;
  const int l = t & 63, w = t >> 6;
  const int b = blockIdx.x;
  u16* Pw = &Pl[w][0];
  u16* Vw = &Vt[w][0];

  for (int hi = 0; hi < 3; ++hi) {
    const int h = w + hi * 4;
    const u16* base = qkvb + (size_t)b * 49 * 1152 + h * 32 + (l >> 4) * 8;

    // V^T staging: load V[row][sg*8..+8] (zero for row>=49), scatter to [d][k]
#pragma unroll
    for (int i = 0; i < 4; ++i) {
      const int row = i * 16 + (l >> 2);
      const int sg = l & 3;
      u16x8 vv = {0, 0, 0, 0, 0, 0, 0, 0};
      if (row < 49)
        vv = *(const u16x8*)(qkvb + (size_t)(b * 49 + row) * 1152 + 768 + h * 32 + sg * 8);
#pragma unroll
      for (int e = 0; e < 8; ++e) {
        const int d = sg * 8 + e;
        Vw[d * 72 + (d >> 3) * 8 + row] = vv[e];
      }
    }

    // q (A-frag) / k (B-frag) from global
    bf16x8 qa[4], kb[4];
#pragma unroll
    for (int mi = 0; mi < 4; ++mi) {
      const int n = mi * 16 + (l & 15);
      u16x8 z = {0, 0, 0, 0, 0, 0, 0, 0};
      qa[mi] = (n < 49) ? *(const bf16x8*)(base + (size_t)n * 1152) : as_bf(z);
    }
#pragma unroll
    for (int nj = 0; nj < 4; ++nj) {
      const int m = nj * 16 + (l & 15);
      u16x8 z = {0, 0, 0, 0, 0, 0, 0, 0};
      kb[nj] = (m < 49) ? *(const bf16x8*)(base + 384 + (size_t)m * 1152) : as_bf(z);
    }

    // S = q k^T
    f32x4 s[4][4];
    __builtin_amdgcn_s_setprio(1);
#pragma unroll
    for (int mi = 0; mi < 4; ++mi)
#pragma unroll
      for (int nj = 0; nj < 4; ++nj) s[mi][nj] = MFMA16(qa[mi], kb[nj], zf4(), 0, 0, 0);
    __builtin_amdgcn_s_setprio(0);

    // bias + shift mask
    const float* sm = smask + ((size_t)(b & 3) * 12 + h) * 2401;
#pragma unroll
    for (int mi = 0; mi < 4; ++mi) {
#pragma unroll
      for (int r = 0; r < 4; ++r) {
        const int n = mi * 16 + (l >> 4) * 4 + r;
        if (n < 49) {
#pragma unroll
          for (int nj = 0; nj < 4; ++nj) {
            const int m = nj * 16 + (l & 15);
            s[mi][nj][r] = (m < 49) ? s[mi][nj][r] + sm[n * 49 + m] : -1e30f;
          }
        }
      }
    }
    // softmax: per-row reduce over 4 local cols + 16 lanes (DPP, VALU-only)
#pragma unroll
    for (int mi = 0; mi < 4; ++mi) {
#pragma unroll
      for (int r = 0; r < 4; ++r) {
        float mx = fmaxf(fmaxf(s[mi][0][r], s[mi][1][r]), fmaxf(s[mi][2][r], s[mi][3][r]));
        mx = rmax16(mx);
        float e0 = 0.f;
#pragma unroll
        for (int nj = 0; nj < 4; ++nj) {
          const float p = __expf(s[mi][nj][r] - mx);
          s[mi][nj][r] = p;
          e0 += p;
        }
        e0 = rsum16(e0);
        const float inv = 1.0f / e0;
#pragma unroll
        for (int nj = 0; nj < 4; ++nj) s[mi][nj][r] *= inv;
      }
    }
    // P -> LDS bf16 ([n][k], stride 72)
#pragma unroll
    for (int mi = 0; mi < 4; ++mi)
#pragma unroll
      for (int r = 0; r < 4; ++r) {
        const int row = mi * 16 + (l >> 4) * 4 + r;
#pragma unroll
        for (int nj = 0; nj < 4; ++nj)
          Pw[row * 72 + nj * 16 + (l & 15)] = f2bf(s[mi][nj][r]);
      }
    // drain wave-local LDS writes (V^T + P); waves own disjoint regions
    asm volatile("s_waitcnt lgkmcnt(0)" ::: "memory");
    __builtin_amdgcn_sched_barrier(0);

    // O^T[d][n] = sum_k V^T[d][k] P^T[k][n]
    f32x4 ot[2][4];
#pragma unroll
    for (int dj = 0; dj < 2; ++dj)
#pragma unroll
      for (int mi = 0; mi < 4; ++mi) ot[dj][mi] = zf4();
#pragma unroll
    for (int ks = 0; ks < 2; ++ks) {
      bf16x8 va[2], pb[4];
#pragma unroll
      for (int dj = 0; dj < 2; ++dj) {
        const int d0 = dj * 16 + (l & 15);
        va[dj] = *(const bf16x8*)(Vw + d0 * 72 + (d0 >> 3) * 8 + ks * 32 + (l >> 4) * 8);
      }
#pragma unroll
      for (int mi = 0; mi < 4; ++mi)
        pb[mi] = *(const bf16x8*)(Pw + (mi * 16 + (l & 15)) * 72 + ks * 32 + (l >> 4) * 8);
      __builtin_amdgcn_s_setprio(1);
#pragma unroll
      for (int dj = 0; dj < 2; ++dj)
#pragma unroll
        for (int mi = 0; mi < 4; ++mi)
          ot[dj][mi] = MFMA16(va[dj], pb[mi], ot[dj][mi], 0, 0, 0);
      __builtin_amdgcn_s_setprio(0);
    }
    // store: lane holds O^T[d = dj*16+(l>>4)*4+r][n = mi*16+(l&15)]
#pragma unroll
    for (int dj = 0; dj < 2; ++dj)
#pragma unroll
      for (int mi = 0; mi < 4; ++mi) {
        const int n = mi * 16 + (l & 15);
        if (n < 49) {
          u16x4 pk;
          pk[0] = f2bf(ot[dj][mi][0]);
          pk[1] = f2bf(ot[dj][mi][1]);
          pk[2] = f2bf(ot[dj][mi][2]);
          pk[3] = f2bf(ot[dj][mi][3]);
          *(u16x4*)(attnb + (size_t)(b * 49 + n) * 384 + h * 32 + dj * 16 + (l >> 4) * 4) = pk;
        }
      }
    // all LDS reads of this iter retired before next iter overwrites
    asm volatile("s_waitcnt lgkmcnt(0)" ::: "memory");
    __builtin_amdgcn_sched_barrier(0);
  }
}

extern "C" void kernel_launch(void* const* d_in, const int* in_sizes, int n_in,
                              void* d_out, int out_size, void* d_ws, size_t ws_size,
                              hipStream_t stream) {
  const float* x       = (const float*)d_in[0];
  const float* mask    = (const float*)d_in[1];
  const float* w_qkv   = (const float*)d_in[2];
  const float* b_qkv   = (const float*)d_in[3];
  const float* bias_t  = (const float*)d_in[4];
  const float* w_proj  = (const float*)d_in[5];
  const float* b_proj  = (const float*)d_in[6];
  const int*   rel_idx = (const int*)d_in[7];
  float* out = (float*)d_out;

  char* ws = (char*)d_ws;
  u16*   wqT   = (u16*)ws;                       // 442368 u16
  u16*   wpT   = (u16*)(ws + 884736);            // 147456 u16
  float* smask = (float*)(ws + 1179648);         // 115248 f32
  u16*   qkvb  = (u16*)(ws + 1640640);           // 200704*1152 u16
  u16*   xb    = (u16*)(ws + 464062656);         // 200704*384 u16 (aliases attnb)
  u16*   attnb = (u16*)(ws + 464062656);         // xb dead before attn writes

  prep_kernel<<<2755, 256, 0, stream>>>(w_qkv, w_proj, bias_t, rel_idx, mask,
                                        wqT, wpT, smask);
  conv_x<<<37632, 256, 0, stream>>>(x, xb);
  gemm4<9, true><<<14112, 256, 0, stream>>>(wqT, xb, b_qkv, qkvb);
  attn_kernel<<<4096, 256, 0, stream>>>(qkvb, smask, attnb);
  gemm4<3, false><<<4704, 256, 0, stream>>>(wpT, attnb, b_proj, out);
}